// Round 1
// baseline (421.365 us; speedup 1.0000x reference)
//
#include <hip/hip_runtime.h>

// VQ: x (32,64,64,64) fp32 NCHW, embed (512,64) fp32.
// N = 131072 rows of D=64; K=512 codes.
// out = [quantized: N*64 floats (NHWC)] ++ [indices: N floats]

#define VQ_N 131072
#define VQ_D 64
#define VQ_K 512
#define VQ_HW 4096   // H*W = 64*64

__global__ __launch_bounds__(256) void vq_esq_kernel(
    const float* __restrict__ embed, float* __restrict__ esq) {
    int k = blockIdx.x * blockDim.x + threadIdx.x;
    if (k >= VQ_K) return;
    const float* e = embed + k * VQ_D;
    float p0 = 0.f, p1 = 0.f, p2 = 0.f, p3 = 0.f;
#pragma unroll
    for (int d = 0; d < VQ_D; d += 4) {
        p0 = fmaf(e[d + 0], e[d + 0], p0);
        p1 = fmaf(e[d + 1], e[d + 1], p1);
        p2 = fmaf(e[d + 2], e[d + 2], p2);
        p3 = fmaf(e[d + 3], e[d + 3], p3);
    }
    esq[k] = (p0 + p1) + (p2 + p3);
}

__global__ __launch_bounds__(256) void vq_main_kernel(
    const float* __restrict__ x,
    const float* __restrict__ embed,
    const float* __restrict__ esq,
    float* __restrict__ out_q,
    float* __restrict__ out_idx) {
    const int n  = blockIdx.x * 256 + threadIdx.x;
    const int b  = n >> 12;        // n / 4096
    const int hw = n & 4095;       // h*64 + w  (lanes consecutive in w -> coalesced)

    // Load row x[b, :, h, w] — stride H*W between channels, coalesced across lanes.
    const float* xp = x + b * (VQ_D * VQ_HW) + hw;
    float xr[VQ_D];
#pragma unroll
    for (int c = 0; c < VQ_D; ++c) xr[c] = xp[c * VQ_HW];

    float best = 3.4e38f;
    int bidx = 0;

    // 8 independent dot-product chains per iteration; embed/esq addresses are
    // wave-uniform -> scalar loads, FMA uses the one-SGPR operand slot.
    for (int k0 = 0; k0 < VQ_K; k0 += 8) {
        float acc0 = 0.f, acc1 = 0.f, acc2 = 0.f, acc3 = 0.f;
        float acc4 = 0.f, acc5 = 0.f, acc6 = 0.f, acc7 = 0.f;
        const float* e0 = embed + k0 * VQ_D;
#pragma unroll
        for (int d = 0; d < VQ_D; ++d) {
            const float xv = xr[d];
            acc0 = fmaf(xv, e0[0 * VQ_D + d], acc0);
            acc1 = fmaf(xv, e0[1 * VQ_D + d], acc1);
            acc2 = fmaf(xv, e0[2 * VQ_D + d], acc2);
            acc3 = fmaf(xv, e0[3 * VQ_D + d], acc3);
            acc4 = fmaf(xv, e0[4 * VQ_D + d], acc4);
            acc5 = fmaf(xv, e0[5 * VQ_D + d], acc5);
            acc6 = fmaf(xv, e0[6 * VQ_D + d], acc6);
            acc7 = fmaf(xv, e0[7 * VQ_D + d], acc7);
        }
        float dist;
        // ascending k order + strict < keeps numpy first-min argmin semantics
        dist = fmaf(-2.f, acc0, esq[k0 + 0]); if (dist < best) { best = dist; bidx = k0 + 0; }
        dist = fmaf(-2.f, acc1, esq[k0 + 1]); if (dist < best) { best = dist; bidx = k0 + 1; }
        dist = fmaf(-2.f, acc2, esq[k0 + 2]); if (dist < best) { best = dist; bidx = k0 + 2; }
        dist = fmaf(-2.f, acc3, esq[k0 + 3]); if (dist < best) { best = dist; bidx = k0 + 3; }
        dist = fmaf(-2.f, acc4, esq[k0 + 4]); if (dist < best) { best = dist; bidx = k0 + 4; }
        dist = fmaf(-2.f, acc5, esq[k0 + 5]); if (dist < best) { best = dist; bidx = k0 + 5; }
        dist = fmaf(-2.f, acc6, esq[k0 + 6]); if (dist < best) { best = dist; bidx = k0 + 6; }
        dist = fmaf(-2.f, acc7, esq[k0 + 7]); if (dist < best) { best = dist; bidx = k0 + 7; }
    }

    // indices (as exact float values 0..511)
    out_idx[n] = (float)bidx;

    // quantized row = embed[bidx], 16 x float4 gather/store
    const float4* e4 = (const float4*)(embed + bidx * VQ_D);
    float4* o4 = (float4*)(out_q + (size_t)n * VQ_D);
#pragma unroll
    for (int c = 0; c < VQ_D / 4; ++c) o4[c] = e4[c];
}

extern "C" void kernel_launch(void* const* d_in, const int* in_sizes, int n_in,
                              void* d_out, int out_size, void* d_ws, size_t ws_size,
                              hipStream_t stream) {
    const float* x     = (const float*)d_in[0];
    const float* embed = (const float*)d_in[1];
    float* out_q   = (float*)d_out;                 // N*64 quantized
    float* out_idx = (float*)d_out + (size_t)VQ_N * VQ_D;  // N indices
    float* esq     = (float*)d_ws;                  // K floats scratch

    vq_esq_kernel<<<2, 256, 0, stream>>>(embed, esq);
    vq_main_kernel<<<VQ_N / 256, 256, 0, stream>>>(x, embed, esq, out_q, out_idx);
}